// Round 2
// baseline (676.981 us; speedup 1.0000x reference)
//
#include <hip/hip_runtime.h>
#include <math.h>

// Problem constants (from reference: N=200000, D=256, 2 heads, 2 att iters)
#define NROWS 200000
#define D 256
#define F4_PER_ROW 64   // 256 floats / 4

// Workspace layout (floats)
#define WS_C     0        // 256  : column sum of x
#define WS_OUT1  256      // 512  : per-head out1 = sum(a1 * x)
#define WS_OUT2  768      // 512  : per-head out2 = sum(a2 * a1 * x)
#define WS_H1    1280     // 512  : per-head h1
#define WS_H2    1792     // 512  : per-head h2
#define WS_A     2304     // 2*N  : a1 per row, head0 then head1
#define ZERO_CNT 1280     // zero c + out1 + out2 each launch

#define PASS_GRID 2048

// att = sigmoid(s / max(|s|, eps))  (L1-normalize of a single-elem row, then sigmoid)
__device__ __forceinline__ float att_sigmoid(float s) {
    float t = s / fmaxf(fabsf(s), 1e-12f);
    return 1.0f / (1.0f + __expf(-t));
}

__device__ __forceinline__ float wave_sum(float v) {
#pragma unroll
    for (int off = 1; off < 64; off <<= 1) v += __shfl_xor(v, off);
    return v;
}

__global__ void zero_kernel(float* __restrict__ ws) {
    int i = blockIdx.x * blockDim.x + threadIdx.x;
    if (i < ZERO_CNT) ws[i] = 0.0f;
}

// Column sums of x -> ws[WS_C..+255]. 4 independent accumulator chains for MLP.
__global__ void __launch_bounds__(256) colsum_kernel(const float* __restrict__ x,
                                                     float* __restrict__ ws) {
    const int total = NROWS * F4_PER_ROW;  // 12.8M float4
    const int tid = threadIdx.x;
    const int stride = gridDim.x * blockDim.x;  // multiple of 64 -> column group fixed
    const float4* x4 = reinterpret_cast<const float4*>(x);
    float4 a0 = make_float4(0.f, 0.f, 0.f, 0.f);
    float4 a1 = a0, a2 = a0, a3 = a0;
    int i = blockIdx.x * blockDim.x + tid;
    for (; i + 3 * stride < total; i += 4 * stride) {
        float4 v0 = x4[i];
        float4 v1 = x4[i + stride];
        float4 v2 = x4[i + 2 * stride];
        float4 v3 = x4[i + 3 * stride];
        a0.x += v0.x; a0.y += v0.y; a0.z += v0.z; a0.w += v0.w;
        a1.x += v1.x; a1.y += v1.y; a1.z += v1.z; a1.w += v1.w;
        a2.x += v2.x; a2.y += v2.y; a2.z += v2.z; a2.w += v2.w;
        a3.x += v3.x; a3.y += v3.y; a3.z += v3.z; a3.w += v3.w;
    }
    for (; i < total; i += stride) {
        float4 v = x4[i];
        a0.x += v.x; a0.y += v.y; a0.z += v.z; a0.w += v.w;
    }
    a0.x += a1.x + a2.x + a3.x;
    a0.y += a1.y + a2.y + a3.y;
    a0.z += a1.z + a2.z + a3.z;
    a0.w += a1.w + a2.w + a3.w;
    __shared__ float4 sh[256];
    sh[tid] = a0;
    __syncthreads();
    if (tid < 64) {
        float4 a = sh[tid], b = sh[tid + 64], c = sh[tid + 128], d = sh[tid + 192];
        atomicAdd(&ws[WS_C + tid * 4 + 0], a.x + b.x + c.x + d.x);
        atomicAdd(&ws[WS_C + tid * 4 + 1], a.y + b.y + c.y + d.y);
        atomicAdd(&ws[WS_C + tid * 4 + 2], a.z + b.z + c.z + d.z);
        atomicAdd(&ws[WS_C + tid * 4 + 3], a.w + b.w + c.w + d.w);
    }
}

// h[head][j] = tanh( sum_k (v[head][k]*scale) * W[head][k][j] )
__global__ void hproj_kernel(const float* __restrict__ W,
                             const float* __restrict__ vin, int vstride, float scale,
                             float* __restrict__ hout) {
    int head = blockIdx.x;
    int j = threadIdx.x;
    __shared__ float v[D];
    v[j] = vin[head * vstride + j] * scale;
    __syncthreads();
    const float* Wh = W + head * D * D;
    float acc = 0.0f;
#pragma unroll 8
    for (int k = 0; k < D; ++k) acc = fmaf(v[k], Wh[k * D + j], acc);
    hout[head * D + j] = tanhf(acc);
}

// Pass 1: per row r: s_i = x[r].h1_i ; a1_i = att_sigmoid(s_i); out1_i += a1_i * x[r]
// One wave per row, 4 rows batched per iteration (4 outstanding loads).
__global__ void __launch_bounds__(256) pass1_kernel(const float* __restrict__ x,
                                                    float* __restrict__ ws) {
    const float* h = ws + WS_H1;
    float* out1 = ws + WS_OUT1;
    float* aArr = ws + WS_A;
    const int tid = threadIdx.x;
    const int lane = tid & 63;
    const int wv = tid >> 6;
    const int gw = blockIdx.x * 4 + wv;
    const int nw = gridDim.x * 4;
    const float4* x4 = reinterpret_cast<const float4*>(x);
    float4 h0v = reinterpret_cast<const float4*>(h)[lane];
    float4 h1v = reinterpret_cast<const float4*>(h + D)[lane];
    float4 acc0 = make_float4(0.f, 0.f, 0.f, 0.f);
    float4 acc1 = make_float4(0.f, 0.f, 0.f, 0.f);
    int r = gw;
    for (; r + 3 * nw < NROWS; r += 4 * nw) {
        float4 xv[4];
#pragma unroll
        for (int j = 0; j < 4; ++j) xv[j] = x4[(size_t)(r + j * nw) * F4_PER_ROW + lane];
        float d0[4], d1[4];
#pragma unroll
        for (int j = 0; j < 4; ++j) {
            d0[j] = fmaf(xv[j].x, h0v.x, fmaf(xv[j].y, h0v.y, fmaf(xv[j].z, h0v.z, xv[j].w * h0v.w)));
            d1[j] = fmaf(xv[j].x, h1v.x, fmaf(xv[j].y, h1v.y, fmaf(xv[j].z, h1v.z, xv[j].w * h1v.w)));
        }
#pragma unroll
        for (int j = 0; j < 4; ++j) { d0[j] = wave_sum(d0[j]); d1[j] = wave_sum(d1[j]); }
#pragma unroll
        for (int j = 0; j < 4; ++j) {
            float a0 = att_sigmoid(d0[j]);
            float a1 = att_sigmoid(d1[j]);
            if (lane == 0) aArr[r + j * nw] = a0;
            else if (lane == 1) aArr[NROWS + r + j * nw] = a1;
            acc0.x = fmaf(a0, xv[j].x, acc0.x);
            acc0.y = fmaf(a0, xv[j].y, acc0.y);
            acc0.z = fmaf(a0, xv[j].z, acc0.z);
            acc0.w = fmaf(a0, xv[j].w, acc0.w);
            acc1.x = fmaf(a1, xv[j].x, acc1.x);
            acc1.y = fmaf(a1, xv[j].y, acc1.y);
            acc1.z = fmaf(a1, xv[j].z, acc1.z);
            acc1.w = fmaf(a1, xv[j].w, acc1.w);
        }
    }
    for (; r < NROWS; r += nw) {
        float4 xv = x4[(size_t)r * F4_PER_ROW + lane];
        float d0 = fmaf(xv.x, h0v.x, fmaf(xv.y, h0v.y, fmaf(xv.z, h0v.z, xv.w * h0v.w)));
        float d1 = fmaf(xv.x, h1v.x, fmaf(xv.y, h1v.y, fmaf(xv.z, h1v.z, xv.w * h1v.w)));
        d0 = wave_sum(d0); d1 = wave_sum(d1);
        float a0 = att_sigmoid(d0);
        float a1 = att_sigmoid(d1);
        if (lane == 0) aArr[r] = a0;
        else if (lane == 1) aArr[NROWS + r] = a1;
        acc0.x = fmaf(a0, xv.x, acc0.x); acc0.y = fmaf(a0, xv.y, acc0.y);
        acc0.z = fmaf(a0, xv.z, acc0.z); acc0.w = fmaf(a0, xv.w, acc0.w);
        acc1.x = fmaf(a1, xv.x, acc1.x); acc1.y = fmaf(a1, xv.y, acc1.y);
        acc1.z = fmaf(a1, xv.z, acc1.z); acc1.w = fmaf(a1, xv.w, acc1.w);
    }
    __shared__ float4 sh[2][256];
    sh[0][tid] = acc0;
    sh[1][tid] = acc1;
    __syncthreads();
    if (tid < 128) {
        int hh = tid >> 6;
        int t = tid & 63;
        float4 a = sh[hh][t], b = sh[hh][t + 64], c = sh[hh][t + 128], d = sh[hh][t + 192];
        atomicAdd(&out1[hh * D + t * 4 + 0], a.x + b.x + c.x + d.x);
        atomicAdd(&out1[hh * D + t * 4 + 1], a.y + b.y + c.y + d.y);
        atomicAdd(&out1[hh * D + t * 4 + 2], a.z + b.z + c.z + d.z);
        atomicAdd(&out1[hh * D + t * 4 + 3], a.w + b.w + c.w + d.w);
    }
}

// Pass 2: s_i = a1_i * (x[r].h2_i); a2_i = att_sigmoid(s_i); out2_i += (a2_i*a1_i) * x[r]
__global__ void __launch_bounds__(256) pass2_kernel(const float* __restrict__ x,
                                                    float* __restrict__ ws) {
    const float* h = ws + WS_H2;
    float* out2 = ws + WS_OUT2;
    const float* aArr = ws + WS_A;
    const int tid = threadIdx.x;
    const int lane = tid & 63;
    const int wv = tid >> 6;
    const int gw = blockIdx.x * 4 + wv;
    const int nw = gridDim.x * 4;
    const float4* x4 = reinterpret_cast<const float4*>(x);
    float4 h0v = reinterpret_cast<const float4*>(h)[lane];
    float4 h1v = reinterpret_cast<const float4*>(h + D)[lane];
    float4 acc0 = make_float4(0.f, 0.f, 0.f, 0.f);
    float4 acc1 = make_float4(0.f, 0.f, 0.f, 0.f);
    int r = gw;
    for (; r + 3 * nw < NROWS; r += 4 * nw) {
        float4 xv[4];
        float aa0[4], aa1[4];
#pragma unroll
        for (int j = 0; j < 4; ++j) {
            xv[j] = x4[(size_t)(r + j * nw) * F4_PER_ROW + lane];
            aa0[j] = aArr[r + j * nw];
            aa1[j] = aArr[NROWS + r + j * nw];
        }
        float d0[4], d1[4];
#pragma unroll
        for (int j = 0; j < 4; ++j) {
            d0[j] = fmaf(xv[j].x, h0v.x, fmaf(xv[j].y, h0v.y, fmaf(xv[j].z, h0v.z, xv[j].w * h0v.w)));
            d1[j] = fmaf(xv[j].x, h1v.x, fmaf(xv[j].y, h1v.y, fmaf(xv[j].z, h1v.z, xv[j].w * h1v.w)));
        }
#pragma unroll
        for (int j = 0; j < 4; ++j) { d0[j] = wave_sum(d0[j]); d1[j] = wave_sum(d1[j]); }
#pragma unroll
        for (int j = 0; j < 4; ++j) {
            float w0 = att_sigmoid(aa0[j] * d0[j]) * aa0[j];
            float w1 = att_sigmoid(aa1[j] * d1[j]) * aa1[j];
            acc0.x = fmaf(w0, xv[j].x, acc0.x);
            acc0.y = fmaf(w0, xv[j].y, acc0.y);
            acc0.z = fmaf(w0, xv[j].z, acc0.z);
            acc0.w = fmaf(w0, xv[j].w, acc0.w);
            acc1.x = fmaf(w1, xv[j].x, acc1.x);
            acc1.y = fmaf(w1, xv[j].y, acc1.y);
            acc1.z = fmaf(w1, xv[j].z, acc1.z);
            acc1.w = fmaf(w1, xv[j].w, acc1.w);
        }
    }
    for (; r < NROWS; r += nw) {
        float4 xv = x4[(size_t)r * F4_PER_ROW + lane];
        float aa0 = aArr[r];
        float aa1 = aArr[NROWS + r];
        float d0 = fmaf(xv.x, h0v.x, fmaf(xv.y, h0v.y, fmaf(xv.z, h0v.z, xv.w * h0v.w)));
        float d1 = fmaf(xv.x, h1v.x, fmaf(xv.y, h1v.y, fmaf(xv.z, h1v.z, xv.w * h1v.w)));
        d0 = wave_sum(d0); d1 = wave_sum(d1);
        float w0 = att_sigmoid(aa0 * d0) * aa0;
        float w1 = att_sigmoid(aa1 * d1) * aa1;
        acc0.x = fmaf(w0, xv.x, acc0.x); acc0.y = fmaf(w0, xv.y, acc0.y);
        acc0.z = fmaf(w0, xv.z, acc0.z); acc0.w = fmaf(w0, xv.w, acc0.w);
        acc1.x = fmaf(w1, xv.x, acc1.x); acc1.y = fmaf(w1, xv.y, acc1.y);
        acc1.z = fmaf(w1, xv.z, acc1.z); acc1.w = fmaf(w1, xv.w, acc1.w);
    }
    __shared__ float4 sh[2][256];
    sh[0][tid] = acc0;
    sh[1][tid] = acc1;
    __syncthreads();
    if (tid < 128) {
        int hh = tid >> 6;
        int t = tid & 63;
        float4 a = sh[hh][t], b = sh[hh][t + 64], c = sh[hh][t + 128], d = sh[hh][t + 192];
        atomicAdd(&out2[hh * D + t * 4 + 0], a.x + b.x + c.x + d.x);
        atomicAdd(&out2[hh * D + t * 4 + 1], a.y + b.y + c.y + d.y);
        atomicAdd(&out2[hh * D + t * 4 + 2], a.z + b.z + c.z + d.z);
        atomicAdd(&out2[hh * D + t * 4 + 3], a.w + b.w + c.w + d.w);
    }
}

__global__ void writeout_kernel(const float* __restrict__ ws, float* __restrict__ out) {
    int i = blockIdx.x * blockDim.x + threadIdx.x;
    if (i < 2 * D) out[i] = ws[WS_OUT2 + i];
}

extern "C" void kernel_launch(void* const* d_in, const int* in_sizes, int n_in,
                              void* d_out, int out_size, void* d_ws, size_t ws_size,
                              hipStream_t stream) {
    const float* x = (const float*)d_in[0];   // (200000, 256) f32
    const float* W = (const float*)d_in[1];   // (2, 256, 256) f32
    float* out = (float*)d_out;               // (1, 512) f32
    float* ws = (float*)d_ws;

    zero_kernel<<<dim3((ZERO_CNT + 255) / 256), dim3(256), 0, stream>>>(ws);
    colsum_kernel<<<dim3(PASS_GRID), dim3(256), 0, stream>>>(x, ws);
    hproj_kernel<<<dim3(2), dim3(256), 0, stream>>>(W, ws + WS_C, 0, 1.0f / NROWS, ws + WS_H1);
    pass1_kernel<<<dim3(PASS_GRID), dim3(256), 0, stream>>>(x, ws);
    hproj_kernel<<<dim3(2), dim3(256), 0, stream>>>(W, ws + WS_OUT1, D, 1.0f / NROWS, ws + WS_H2);
    pass2_kernel<<<dim3(PASS_GRID), dim3(256), 0, stream>>>(x, ws);
    writeout_kernel<<<dim3(2), dim3(256), 0, stream>>>(ws, out);
}

// Round 3
// 186.057 us; speedup vs baseline: 3.6386x; 3.6386x over previous
//
#include <hip/hip_runtime.h>
#include <math.h>

// Problem constants (reference: N=200000, D=256, 2 heads, 2 att iters)
#define NROWS 200000
#define D 256
#define F4_PER_ROW 64

// Grid geometry: 500 blocks x 400 rows = 200000 exactly.
// Each block: 4 waves; each wave: 25 iters x 4 consecutive rows.
#define NBLK 500
#define CHUNK 400
#define ITERS 25
#define RPB 8          // partial-rows per reduce block
#define RED_BLOCKS ((NBLK + RPB - 1) / RPB)   // 63

// Workspace layout (floats)
#define WS_C     0        // 256  : column sum of x
#define WS_OUT1  256      // 512  : per-head out1
#define WS_OUT2  768      // 512  : (unused as atomic dst now; kept for layout)
#define WS_H1    1280     // 512  : per-head h1
#define WS_H2    1792     // 512  : per-head h2
#define WS_A     2304     // 2*N  : a1 per row, head0 then head1
#define WS_PART  402304   // up to 500*512 floats of per-block partials
#define ZERO_CNT 1280

__device__ __forceinline__ float att_sigmoid(float s) {
    float t = s / fmaxf(fabsf(s), 1e-12f);
    return 1.0f / (1.0f + __expf(-t));
}

__device__ __forceinline__ float wave_sum(float v) {
#pragma unroll
    for (int off = 1; off < 64; off <<= 1) v += __shfl_xor(v, off);
    return v;
}

__global__ void zero_kernel(float* __restrict__ ws, float* __restrict__ out) {
    int i = blockIdx.x * blockDim.x + threadIdx.x;
    if (i < ZERO_CNT) ws[i] = 0.0f;
    if (i < 2 * D) out[i] = 0.0f;
}

// Stage A colsum: per-block partial column sums -> part[b*256 + c] (no atomics)
__global__ void __launch_bounds__(256) colsum_kernel(const float* __restrict__ x,
                                                     float* __restrict__ part) {
    const int tid = threadIdx.x;
    const int lane = tid & 63;
    const int wv = tid >> 6;
    const int r0 = blockIdx.x * CHUNK + wv * 4;
    const float4* x4 = reinterpret_cast<const float4*>(x);
    float4 acc = make_float4(0.f, 0.f, 0.f, 0.f);
#pragma unroll 2
    for (int it = 0; it < ITERS; ++it) {
        size_t rb = (size_t)(r0 + it * 16) * F4_PER_ROW + lane;
        float4 v0 = x4[rb];
        float4 v1 = x4[rb + F4_PER_ROW];
        float4 v2 = x4[rb + 2 * F4_PER_ROW];
        float4 v3 = x4[rb + 3 * F4_PER_ROW];
        acc.x += (v0.x + v1.x) + (v2.x + v3.x);
        acc.y += (v0.y + v1.y) + (v2.y + v3.y);
        acc.z += (v0.z + v1.z) + (v2.z + v3.z);
        acc.w += (v0.w + v1.w) + (v2.w + v3.w);
    }
    __shared__ float4 sh[256];
    sh[tid] = acc;
    __syncthreads();
    if (tid < 64) {
        float4 a = sh[tid], b = sh[tid + 64], c = sh[tid + 128], d = sh[tid + 192];
        float4 s;
        s.x = (a.x + b.x) + (c.x + d.x);
        s.y = (a.y + b.y) + (c.y + d.y);
        s.z = (a.z + b.z) + (c.z + d.z);
        s.w = (a.w + b.w) + (c.w + d.w);
        reinterpret_cast<float4*>(part + blockIdx.x * 256)[tid] = s;
    }
}

// Stage B: dst[c] += sum over partial rows (few atomics: RED_BLOCKS per address)
__global__ void __launch_bounds__(256) reduce_parts(const float* __restrict__ src,
                                                    float* __restrict__ dst,
                                                    int nparts, int width) {
    const int tid = threadIdx.x;
    const int rlo = blockIdx.x * RPB;
    const int rhi = (rlo + RPB < nparts) ? (rlo + RPB) : nparts;
    for (int c = tid; c < width; c += 256) {
        float s0 = 0.f, s1 = 0.f;
        int r = rlo;
        for (; r + 1 < rhi; r += 2) {
            s0 += src[(size_t)r * width + c];
            s1 += src[(size_t)(r + 1) * width + c];
        }
        if (r < rhi) s0 += src[(size_t)r * width + c];
        atomicAdd(&dst[c], s0 + s1);
    }
}

// h[head][j] = tanh( sum_k (v[head][k]*scale) * W[head][k][j] )
__global__ void hproj_kernel(const float* __restrict__ W,
                             const float* __restrict__ vin, int vstride, float scale,
                             float* __restrict__ hout) {
    int head = blockIdx.x;
    int j = threadIdx.x;
    __shared__ float v[D];
    v[j] = vin[head * vstride + j] * scale;
    __syncthreads();
    const float* Wh = W + head * D * D;
    float acc = 0.0f;
#pragma unroll 8
    for (int k = 0; k < D; ++k) acc = fmaf(v[k], Wh[k * D + j], acc);
    hout[head * D + j] = tanhf(acc);
}

// Pass 1: a1 = att_sigmoid(x.h1); out1_part = sum(a1*x); store a1.
__global__ void __launch_bounds__(256) pass1_kernel(const float* __restrict__ x,
                                                    float* __restrict__ ws) {
    const float* h = ws + WS_H1;
    float* aA0 = ws + WS_A;
    float* aA1 = ws + WS_A + NROWS;
    float* part = ws + WS_PART;
    const int tid = threadIdx.x;
    const int lane = tid & 63;
    const int wv = tid >> 6;
    const int r0 = blockIdx.x * CHUNK + wv * 4;
    const float4* x4 = reinterpret_cast<const float4*>(x);
    float4 h0v = reinterpret_cast<const float4*>(h)[lane];
    float4 h1v = reinterpret_cast<const float4*>(h + D)[lane];
    float4 acc0 = make_float4(0.f, 0.f, 0.f, 0.f);
    float4 acc1 = make_float4(0.f, 0.f, 0.f, 0.f);
    for (int it = 0; it < ITERS; ++it) {
        const int rb = r0 + it * 16;
        float4 xv[4];
#pragma unroll
        for (int j = 0; j < 4; ++j) xv[j] = x4[(size_t)(rb + j) * F4_PER_ROW + lane];
        float d0[4], d1[4];
#pragma unroll
        for (int j = 0; j < 4; ++j) {
            d0[j] = fmaf(xv[j].x, h0v.x, fmaf(xv[j].y, h0v.y, fmaf(xv[j].z, h0v.z, xv[j].w * h0v.w)));
            d1[j] = fmaf(xv[j].x, h1v.x, fmaf(xv[j].y, h1v.y, fmaf(xv[j].z, h1v.z, xv[j].w * h1v.w)));
        }
#pragma unroll
        for (int j = 0; j < 4; ++j) { d0[j] = wave_sum(d0[j]); d1[j] = wave_sum(d1[j]); }
        float a0[4], a1[4];
#pragma unroll
        for (int j = 0; j < 4; ++j) {
            a0[j] = att_sigmoid(d0[j]);
            a1[j] = att_sigmoid(d1[j]);
            acc0.x = fmaf(a0[j], xv[j].x, acc0.x);
            acc0.y = fmaf(a0[j], xv[j].y, acc0.y);
            acc0.z = fmaf(a0[j], xv[j].z, acc0.z);
            acc0.w = fmaf(a0[j], xv[j].w, acc0.w);
            acc1.x = fmaf(a1[j], xv[j].x, acc1.x);
            acc1.y = fmaf(a1[j], xv[j].y, acc1.y);
            acc1.z = fmaf(a1[j], xv[j].z, acc1.z);
            acc1.w = fmaf(a1[j], xv[j].w, acc1.w);
        }
        if (lane == 0) {
            *reinterpret_cast<float4*>(aA0 + rb) = make_float4(a0[0], a0[1], a0[2], a0[3]);
        } else if (lane == 1) {
            *reinterpret_cast<float4*>(aA1 + rb) = make_float4(a1[0], a1[1], a1[2], a1[3]);
        }
    }
    __shared__ float4 sh[2][256];
    sh[0][tid] = acc0;
    sh[1][tid] = acc1;
    __syncthreads();
    if (tid < 128) {
        int hh = tid >> 6;
        int t = tid & 63;
        float4 a = sh[hh][t], b = sh[hh][t + 64], c = sh[hh][t + 128], d = sh[hh][t + 192];
        float4 s;
        s.x = (a.x + b.x) + (c.x + d.x);
        s.y = (a.y + b.y) + (c.y + d.y);
        s.z = (a.z + b.z) + (c.z + d.z);
        s.w = (a.w + b.w) + (c.w + d.w);
        reinterpret_cast<float4*>(part + blockIdx.x * 512)[tid] = s;
    }
}

// Pass 2: a2 = att_sigmoid(a1*(x.h2)); out2_part = sum(a2*a1*x)
__global__ void __launch_bounds__(256) pass2_kernel(const float* __restrict__ x,
                                                    float* __restrict__ ws) {
    const float* h = ws + WS_H2;
    const float* aA0 = ws + WS_A;
    const float* aA1 = ws + WS_A + NROWS;
    float* part = ws + WS_PART;
    const int tid = threadIdx.x;
    const int lane = tid & 63;
    const int wv = tid >> 6;
    const int r0 = blockIdx.x * CHUNK + wv * 4;
    const float4* x4 = reinterpret_cast<const float4*>(x);
    float4 h0v = reinterpret_cast<const float4*>(h)[lane];
    float4 h1v = reinterpret_cast<const float4*>(h + D)[lane];
    float4 acc0 = make_float4(0.f, 0.f, 0.f, 0.f);
    float4 acc1 = make_float4(0.f, 0.f, 0.f, 0.f);
    for (int it = 0; it < ITERS; ++it) {
        const int rb = r0 + it * 16;
        float4 xv[4];
#pragma unroll
        for (int j = 0; j < 4; ++j) xv[j] = x4[(size_t)(rb + j) * F4_PER_ROW + lane];
        float4 aa0 = *reinterpret_cast<const float4*>(aA0 + rb);
        float4 aa1 = *reinterpret_cast<const float4*>(aA1 + rb);
        float d0[4], d1[4];
#pragma unroll
        for (int j = 0; j < 4; ++j) {
            d0[j] = fmaf(xv[j].x, h0v.x, fmaf(xv[j].y, h0v.y, fmaf(xv[j].z, h0v.z, xv[j].w * h0v.w)));
            d1[j] = fmaf(xv[j].x, h1v.x, fmaf(xv[j].y, h1v.y, fmaf(xv[j].z, h1v.z, xv[j].w * h1v.w)));
        }
#pragma unroll
        for (int j = 0; j < 4; ++j) { d0[j] = wave_sum(d0[j]); d1[j] = wave_sum(d1[j]); }
        float w0[4], w1[4];
        w0[0] = att_sigmoid(aa0.x * d0[0]) * aa0.x;
        w0[1] = att_sigmoid(aa0.y * d0[1]) * aa0.y;
        w0[2] = att_sigmoid(aa0.z * d0[2]) * aa0.z;
        w0[3] = att_sigmoid(aa0.w * d0[3]) * aa0.w;
        w1[0] = att_sigmoid(aa1.x * d1[0]) * aa1.x;
        w1[1] = att_sigmoid(aa1.y * d1[1]) * aa1.y;
        w1[2] = att_sigmoid(aa1.z * d1[2]) * aa1.z;
        w1[3] = att_sigmoid(aa1.w * d1[3]) * aa1.w;
#pragma unroll
        for (int j = 0; j < 4; ++j) {
            acc0.x = fmaf(w0[j], xv[j].x, acc0.x);
            acc0.y = fmaf(w0[j], xv[j].y, acc0.y);
            acc0.z = fmaf(w0[j], xv[j].z, acc0.z);
            acc0.w = fmaf(w0[j], xv[j].w, acc0.w);
            acc1.x = fmaf(w1[j], xv[j].x, acc1.x);
            acc1.y = fmaf(w1[j], xv[j].y, acc1.y);
            acc1.z = fmaf(w1[j], xv[j].z, acc1.z);
            acc1.w = fmaf(w1[j], xv[j].w, acc1.w);
        }
    }
    __shared__ float4 sh[2][256];
    sh[0][tid] = acc0;
    sh[1][tid] = acc1;
    __syncthreads();
    if (tid < 128) {
        int hh = tid >> 6;
        int t = tid & 63;
        float4 a = sh[hh][t], b = sh[hh][t + 64], c = sh[hh][t + 128], d = sh[hh][t + 192];
        float4 s;
        s.x = (a.x + b.x) + (c.x + d.x);
        s.y = (a.y + b.y) + (c.y + d.y);
        s.z = (a.z + b.z) + (c.z + d.z);
        s.w = (a.w + b.w) + (c.w + d.w);
        reinterpret_cast<float4*>(part + blockIdx.x * 512)[tid] = s;
    }
}

extern "C" void kernel_launch(void* const* d_in, const int* in_sizes, int n_in,
                              void* d_out, int out_size, void* d_ws, size_t ws_size,
                              hipStream_t stream) {
    const float* x = (const float*)d_in[0];   // (200000, 256) f32
    const float* W = (const float*)d_in[1];   // (2, 256, 256) f32
    float* out = (float*)d_out;               // (1, 512) f32
    float* ws = (float*)d_ws;

    zero_kernel<<<dim3(5), dim3(256), 0, stream>>>(ws, out);
    colsum_kernel<<<dim3(NBLK), dim3(256), 0, stream>>>(x, ws + WS_PART);
    reduce_parts<<<dim3(RED_BLOCKS), dim3(256), 0, stream>>>(ws + WS_PART, ws + WS_C, NBLK, 256);
    hproj_kernel<<<dim3(2), dim3(256), 0, stream>>>(W, ws + WS_C, 0, 1.0f / NROWS, ws + WS_H1);
    pass1_kernel<<<dim3(NBLK), dim3(256), 0, stream>>>(x, ws);
    reduce_parts<<<dim3(RED_BLOCKS), dim3(256), 0, stream>>>(ws + WS_PART, ws + WS_OUT1, NBLK, 512);
    hproj_kernel<<<dim3(2), dim3(256), 0, stream>>>(W, ws + WS_OUT1, D, 1.0f / NROWS, ws + WS_H2);
    pass2_kernel<<<dim3(NBLK), dim3(256), 0, stream>>>(x, ws);
    reduce_parts<<<dim3(RED_BLOCKS), dim3(256), 0, stream>>>(ws + WS_PART, out, NBLK, 512);
}

// Round 4
// 167.190 us; speedup vs baseline: 4.0492x; 1.1128x over previous
//
#include <hip/hip_runtime.h>
#include <math.h>

// Problem constants (reference: N=200000, D=256, 2 heads, 2 att iters)
#define NROWS 200000
#define D 256
#define F4 64          // float4 per row

// Grid geometry: 500 blocks x 400 rows = 200000 exactly.
// Block = 4 waves; wave handles 4 consecutive rows per iteration, 25 iters.
#define NBLK 500
#define CHUNK 400
#define ITERS 25

// Workspace layout (floats). No atomics anywhere -> no zeroing needed.
#define WS_H1 0         // 512  per-head h1
#define WS_H2 512       // 512  per-head h2
#define WS_A  1024      // 2*N  a1 per row (head0 then head1)
#define WS_P1 401024    // 500*256 colsum partials
#define WS_P2 529024    // 500*512 pass partials (reused by pass1 then pass2)

__device__ __forceinline__ float att_sigmoid(float s) {
    float t = s / fmaxf(fabsf(s), 1e-12f);
    return 1.0f / (1.0f + __expf(-t));
}

__device__ __forceinline__ float wave_sum(float v) {
#pragma unroll
    for (int off = 1; off < 64; off <<= 1) v += __shfl_xor(v, off);
    return v;
}

__device__ __forceinline__ float dot4(float4 a, float4 b) {
    return fmaf(a.x, b.x, fmaf(a.y, b.y, fmaf(a.z, b.z, a.w * b.w)));
}

// ---- colsum: per-block partial column sums (register double-buffered) ----
__global__ void __launch_bounds__(256) colsum_kernel(const float* __restrict__ x,
                                                     float* __restrict__ part) {
    const int tid = threadIdx.x, lane = tid & 63, wv = tid >> 6;
    const float4* x4 = reinterpret_cast<const float4*>(x);
    const size_t base = (size_t)(blockIdx.x * CHUNK + wv * 4) * F4 + lane;
    float4 cur[4], nxt[4];
#pragma unroll
    for (int j = 0; j < 4; ++j) cur[j] = x4[base + j * F4];
    float4 accA = make_float4(0.f, 0.f, 0.f, 0.f);
    float4 accB = make_float4(0.f, 0.f, 0.f, 0.f);
    for (int it = 0; it < ITERS; ++it) {
        if (it + 1 < ITERS) {
            size_t nb = base + (size_t)(it + 1) * 16 * F4;
#pragma unroll
            for (int j = 0; j < 4; ++j) nxt[j] = x4[nb + j * F4];
        }
        accA.x += cur[0].x + cur[1].x; accB.x += cur[2].x + cur[3].x;
        accA.y += cur[0].y + cur[1].y; accB.y += cur[2].y + cur[3].y;
        accA.z += cur[0].z + cur[1].z; accB.z += cur[2].z + cur[3].z;
        accA.w += cur[0].w + cur[1].w; accB.w += cur[2].w + cur[3].w;
        if (it + 1 < ITERS) {
#pragma unroll
            for (int j = 0; j < 4; ++j) cur[j] = nxt[j];
        }
    }
    accA.x += accB.x; accA.y += accB.y; accA.z += accB.z; accA.w += accB.w;
    __shared__ float4 sh[256];
    sh[tid] = accA;
    __syncthreads();
    if (tid < 64) {
        float4 a = sh[tid], b = sh[tid + 64], c = sh[tid + 128], d = sh[tid + 192];
        float4 s;
        s.x = (a.x + b.x) + (c.x + d.x);
        s.y = (a.y + b.y) + (c.y + d.y);
        s.z = (a.z + b.z) + (c.z + d.z);
        s.w = (a.w + b.w) + (c.w + d.w);
        reinterpret_cast<float4*>(part + blockIdx.x * 256)[tid] = s;
    }
}

// ---- fused: reduce NBLK partial rows -> v, then h = tanh((v*scale) @ W) ----
// width: floats per partial row; headColMul: 0 (shared vec) or 256 (per-head)
__global__ void __launch_bounds__(256) hproj_fused(const float* __restrict__ W,
                                                   const float* __restrict__ part,
                                                   int width, int headColMul, float scale,
                                                   float* __restrict__ hout) {
    const int head = blockIdx.x;
    const int tid = threadIdx.x, lane = tid & 63, wv = tid >> 6;
    const float* p = part + head * headColMul + lane * 4;
    float4 s = make_float4(0.f, 0.f, 0.f, 0.f);
    // wave wv reduces rows {wv, wv+4, ...}: 125 rows, batched 5 at a time
    for (int i = 0; i < 25; ++i) {
        float4 v[5];
#pragma unroll
        for (int k = 0; k < 5; ++k)
            v[k] = *reinterpret_cast<const float4*>(p + (size_t)(wv + (i * 5 + k) * 4) * width);
#pragma unroll
        for (int k = 0; k < 5; ++k) {
            s.x += v[k].x; s.y += v[k].y; s.z += v[k].z; s.w += v[k].w;
        }
    }
    __shared__ float4 red[4][64];
    __shared__ float vbuf[D];
    red[wv][lane] = s;
    __syncthreads();
    if (tid < 64) {
        float4 a = red[0][tid], b = red[1][tid], c = red[2][tid], d = red[3][tid];
        vbuf[tid * 4 + 0] = ((a.x + b.x) + (c.x + d.x)) * scale;
        vbuf[tid * 4 + 1] = ((a.y + b.y) + (c.y + d.y)) * scale;
        vbuf[tid * 4 + 2] = ((a.z + b.z) + (c.z + d.z)) * scale;
        vbuf[tid * 4 + 3] = ((a.w + b.w) + (c.w + d.w)) * scale;
    }
    __syncthreads();
    const float* Wh = W + head * D * D;
    float acc = 0.0f;
#pragma unroll 8
    for (int k = 0; k < D; ++k) acc = fmaf(vbuf[k], Wh[k * D + tid], acc);
    hout[head * D + tid] = tanhf(acc);
}

// ---- pass1: a1 = att_sigmoid(x.h1); partials of sum(a1*x); store a1 ----
__global__ void __launch_bounds__(256) pass1_kernel(const float* __restrict__ x,
                                                    float* __restrict__ ws) {
    const float* h = ws + WS_H1;
    float* aA0 = ws + WS_A;
    float* aA1 = ws + WS_A + NROWS;
    float* part = ws + WS_P2;
    const int tid = threadIdx.x, lane = tid & 63, wv = tid >> 6;
    const int r0 = blockIdx.x * CHUNK + wv * 4;
    const float4* x4 = reinterpret_cast<const float4*>(x);
    const float4 h0v = reinterpret_cast<const float4*>(h)[lane];
    const float4 h1v = reinterpret_cast<const float4*>(h + D)[lane];
    float4 acc0 = make_float4(0.f, 0.f, 0.f, 0.f);
    float4 acc1 = make_float4(0.f, 0.f, 0.f, 0.f);
    const size_t base = (size_t)r0 * F4 + lane;
    float4 cur[4], nxt[4];
#pragma unroll
    for (int j = 0; j < 4; ++j) cur[j] = x4[base + j * F4];
    for (int it = 0; it < ITERS; ++it) {
        if (it + 1 < ITERS) {
            size_t nb = base + (size_t)(it + 1) * 16 * F4;
#pragma unroll
            for (int j = 0; j < 4; ++j) nxt[j] = x4[nb + j * F4];
        }
        float d0[4], d1[4];
#pragma unroll
        for (int j = 0; j < 4; ++j) { d0[j] = dot4(cur[j], h0v); d1[j] = dot4(cur[j], h1v); }
#pragma unroll
        for (int j = 0; j < 4; ++j) { d0[j] = wave_sum(d0[j]); d1[j] = wave_sum(d1[j]); }
        float a0[4], a1[4];
#pragma unroll
        for (int j = 0; j < 4; ++j) {
            a0[j] = att_sigmoid(d0[j]);
            a1[j] = att_sigmoid(d1[j]);
            acc0.x = fmaf(a0[j], cur[j].x, acc0.x);
            acc0.y = fmaf(a0[j], cur[j].y, acc0.y);
            acc0.z = fmaf(a0[j], cur[j].z, acc0.z);
            acc0.w = fmaf(a0[j], cur[j].w, acc0.w);
            acc1.x = fmaf(a1[j], cur[j].x, acc1.x);
            acc1.y = fmaf(a1[j], cur[j].y, acc1.y);
            acc1.z = fmaf(a1[j], cur[j].z, acc1.z);
            acc1.w = fmaf(a1[j], cur[j].w, acc1.w);
        }
        const int rb = r0 + it * 16;
        if (lane == 0)
            *reinterpret_cast<float4*>(aA0 + rb) = make_float4(a0[0], a0[1], a0[2], a0[3]);
        else if (lane == 1)
            *reinterpret_cast<float4*>(aA1 + rb) = make_float4(a1[0], a1[1], a1[2], a1[3]);
        if (it + 1 < ITERS) {
#pragma unroll
            for (int j = 0; j < 4; ++j) cur[j] = nxt[j];
        }
    }
    __shared__ float4 sh[2][256];
    sh[0][tid] = acc0;
    sh[1][tid] = acc1;
    __syncthreads();
    if (tid < 128) {
        int hh = tid >> 6;
        int t = tid & 63;
        float4 a = sh[hh][t], b = sh[hh][t + 64], c = sh[hh][t + 128], d = sh[hh][t + 192];
        float4 s;
        s.x = (a.x + b.x) + (c.x + d.x);
        s.y = (a.y + b.y) + (c.y + d.y);
        s.z = (a.z + b.z) + (c.z + d.z);
        s.w = (a.w + b.w) + (c.w + d.w);
        reinterpret_cast<float4*>(part + blockIdx.x * 512)[tid] = s;
    }
}

// ---- pass2: a2 = att_sigmoid(a1*(x.h2)); partials of sum(a2*a1*x) ----
__global__ void __launch_bounds__(256) pass2_kernel(const float* __restrict__ x,
                                                    float* __restrict__ ws) {
    const float* h = ws + WS_H2;
    const float* aA0 = ws + WS_A;
    const float* aA1 = ws + WS_A + NROWS;
    float* part = ws + WS_P2;
    const int tid = threadIdx.x, lane = tid & 63, wv = tid >> 6;
    const int r0 = blockIdx.x * CHUNK + wv * 4;
    const float4* x4 = reinterpret_cast<const float4*>(x);
    const float4 h0v = reinterpret_cast<const float4*>(h)[lane];
    const float4 h1v = reinterpret_cast<const float4*>(h + D)[lane];
    float4 acc0 = make_float4(0.f, 0.f, 0.f, 0.f);
    float4 acc1 = make_float4(0.f, 0.f, 0.f, 0.f);
    const size_t base = (size_t)r0 * F4 + lane;
    float4 cur[4], nxt[4];
    float4 caa0, caa1, naa0, naa1;
#pragma unroll
    for (int j = 0; j < 4; ++j) cur[j] = x4[base + j * F4];
    caa0 = *reinterpret_cast<const float4*>(aA0 + r0);
    caa1 = *reinterpret_cast<const float4*>(aA1 + r0);
    for (int it = 0; it < ITERS; ++it) {
        if (it + 1 < ITERS) {
            size_t nb = base + (size_t)(it + 1) * 16 * F4;
#pragma unroll
            for (int j = 0; j < 4; ++j) nxt[j] = x4[nb + j * F4];
            naa0 = *reinterpret_cast<const float4*>(aA0 + r0 + (it + 1) * 16);
            naa1 = *reinterpret_cast<const float4*>(aA1 + r0 + (it + 1) * 16);
        }
        float d0[4], d1[4];
#pragma unroll
        for (int j = 0; j < 4; ++j) { d0[j] = dot4(cur[j], h0v); d1[j] = dot4(cur[j], h1v); }
#pragma unroll
        for (int j = 0; j < 4; ++j) { d0[j] = wave_sum(d0[j]); d1[j] = wave_sum(d1[j]); }
        float w0[4], w1[4];
        w0[0] = att_sigmoid(caa0.x * d0[0]) * caa0.x;
        w0[1] = att_sigmoid(caa0.y * d0[1]) * caa0.y;
        w0[2] = att_sigmoid(caa0.z * d0[2]) * caa0.z;
        w0[3] = att_sigmoid(caa0.w * d0[3]) * caa0.w;
        w1[0] = att_sigmoid(caa1.x * d1[0]) * caa1.x;
        w1[1] = att_sigmoid(caa1.y * d1[1]) * caa1.y;
        w1[2] = att_sigmoid(caa1.z * d1[2]) * caa1.z;
        w1[3] = att_sigmoid(caa1.w * d1[3]) * caa1.w;
#pragma unroll
        for (int j = 0; j < 4; ++j) {
            acc0.x = fmaf(w0[j], cur[j].x, acc0.x);
            acc0.y = fmaf(w0[j], cur[j].y, acc0.y);
            acc0.z = fmaf(w0[j], cur[j].z, acc0.z);
            acc0.w = fmaf(w0[j], cur[j].w, acc0.w);
            acc1.x = fmaf(w1[j], cur[j].x, acc1.x);
            acc1.y = fmaf(w1[j], cur[j].y, acc1.y);
            acc1.z = fmaf(w1[j], cur[j].z, acc1.z);
            acc1.w = fmaf(w1[j], cur[j].w, acc1.w);
        }
        if (it + 1 < ITERS) {
#pragma unroll
            for (int j = 0; j < 4; ++j) cur[j] = nxt[j];
            caa0 = naa0; caa1 = naa1;
        }
    }
    __shared__ float4 sh[2][256];
    sh[0][tid] = acc0;
    sh[1][tid] = acc1;
    __syncthreads();
    if (tid < 128) {
        int hh = tid >> 6;
        int t = tid & 63;
        float4 a = sh[hh][t], b = sh[hh][t + 64], c = sh[hh][t + 128], d = sh[hh][t + 192];
        float4 s;
        s.x = (a.x + b.x) + (c.x + d.x);
        s.y = (a.y + b.y) + (c.y + d.y);
        s.z = (a.z + b.z) + (c.z + d.z);
        s.w = (a.w + b.w) + (c.w + d.w);
        reinterpret_cast<float4*>(part + blockIdx.x * 512)[tid] = s;
    }
}

// ---- final: out[head*256+c] = sum over NBLK partial rows (direct store) ----
__global__ void __launch_bounds__(256) out_reduce(const float* __restrict__ part,
                                                  float* __restrict__ out) {
    const int head = blockIdx.x;
    const int tid = threadIdx.x, lane = tid & 63, wv = tid >> 6;
    const float* p = part + head * 256 + lane * 4;
    float4 s = make_float4(0.f, 0.f, 0.f, 0.f);
    for (int i = 0; i < 25; ++i) {
        float4 v[5];
#pragma unroll
        for (int k = 0; k < 5; ++k)
            v[k] = *reinterpret_cast<const float4*>(p + (size_t)(wv + (i * 5 + k) * 4) * 512);
#pragma unroll
        for (int k = 0; k < 5; ++k) {
            s.x += v[k].x; s.y += v[k].y; s.z += v[k].z; s.w += v[k].w;
        }
    }
    __shared__ float4 red[4][64];
    red[wv][lane] = s;
    __syncthreads();
    if (tid < 64) {
        float4 a = red[0][tid], b = red[1][tid], c = red[2][tid], d = red[3][tid];
        float4 o;
        o.x = (a.x + b.x) + (c.x + d.x);
        o.y = (a.y + b.y) + (c.y + d.y);
        o.z = (a.z + b.z) + (c.z + d.z);
        o.w = (a.w + b.w) + (c.w + d.w);
        reinterpret_cast<float4*>(out + head * 256)[tid] = o;
    }
}

extern "C" void kernel_launch(void* const* d_in, const int* in_sizes, int n_in,
                              void* d_out, int out_size, void* d_ws, size_t ws_size,
                              hipStream_t stream) {
    const float* x = (const float*)d_in[0];   // (200000, 256) f32
    const float* W = (const float*)d_in[1];   // (2, 256, 256) f32
    float* out = (float*)d_out;               // (1, 512) f32
    float* ws = (float*)d_ws;

    colsum_kernel<<<dim3(NBLK), dim3(256), 0, stream>>>(x, ws + WS_P1);
    hproj_fused<<<dim3(2), dim3(256), 0, stream>>>(W, ws + WS_P1, 256, 0, 1.0f / NROWS, ws + WS_H1);
    pass1_kernel<<<dim3(NBLK), dim3(256), 0, stream>>>(x, ws);
    hproj_fused<<<dim3(2), dim3(256), 0, stream>>>(W, ws + WS_P2, 512, 256, 1.0f / NROWS, ws + WS_H2);
    pass2_kernel<<<dim3(NBLK), dim3(256), 0, stream>>>(x, ws);
    out_reduce<<<dim3(2), dim3(256), 0, stream>>>(ws + WS_P2, out);
}